// Round 8
// baseline (40.149 us; speedup 1.0000x reference)
//
#include <hip/hip_runtime.h>

#define CHUNK 32                 // elements per wave-chunk (2 lanes/element)
#define NCHUNK 8192              // 262144 / 32
#define SLICE_F 2476             // 800 (D2) + 1568 (D3) + 105 (cg) + 3 pad -> 9904 B (16B aligned)
#define NBLOCKS 1024
#define NWAVES (NBLOCKS * 4)     // 4096 waves -> 2 chunks each

// Barrier-free main kernel: each wave owns a private LDS slice; no
// __syncthreads anywhere, so the 16 waves/CU drift freely and cover each
// other's memory-drain stalls (the diagnosed R1/R5/R7 serialization wall).
// Lane pair (l, l+32) shares element (chunk*32 + (l&31)); sub0 handles
// c in {0..3}, sub1 c in {4..6} (t=3 exec-masked for sub1 -- no branch
// serialization, just one half-utilized unroll step).
__global__ __launch_bounds__(256, 4) void cg_main_kernel(
    const float* __restrict__ D1, const float* __restrict__ D2,
    const float* __restrict__ D3, const float* __restrict__ cg,
    float* __restrict__ partials)
{
    __shared__ __align__(16) float s_all[4][SLICE_F];   // 39616 B -> 4 blocks/CU

    const int tid = threadIdx.x;
    const int wv  = tid >> 6;        // wave in block
    const int l   = tid & 63;        // lane
    const int le  = l & 31;          // element slot in chunk
    const int sub = l >> 5;          // 0 or 1 (c-range selector)

    float* sl  = s_all[wv];
    float* s2  = sl;                 // [32][25] D2
    float* s3  = sl + 800;           // [32][49] D3
    float* scg = sl + 2368;          // [105] cg copy (for divergent-c reads)

    // per-wave cg copy; no barrier needed (wave-private)
    #pragma unroll
    for (int k = 0; k < 2; ++k) {
        int i = k * 64 + l;
        if (i < 105) scg[i] = cg[i];
    }

    const int gw = blockIdx.x * 4 + wv;
    float acc = 0.0f;

    for (int ch = gw; ch < NCHUNK; ch += NWAVES) {
        // ---- coalesced float4 staging into MY slice (no cross-wave sync) ----
        {
            const float4* g2 = (const float4*)(D2 + (size_t)ch * 800);   // 200 f4
            float4* t2 = (float4*)s2;
            #pragma unroll
            for (int k = 0; k < 4; ++k) { int i = k * 64 + l; if (i < 200) t2[i] = g2[i]; }
            const float4* g3 = (const float4*)(D3 + (size_t)ch * 1568);  // 392 f4
            float4* t3 = (float4*)s3;
            #pragma unroll
            for (int k = 0; k < 7; ++k) { int i = k * 64 + l; if (i < 392) t3[i] = g3[i]; }
        }

        // d1 direct (lane pair loads same addresses -> coalescer merges)
        const int e = ch * CHUNK + le;
        float d1[9];
        {
            const float* p1 = D1 + (size_t)e * 9;
            #pragma unroll
            for (int i = 0; i < 9; ++i) d1[i] = p1[i];
        }

        // d2 from LDS: stride 25 (coprime 32) over 32 lanes, pair broadcast -> free
        float d2r[25];
        #pragma unroll
        for (int j = 0; j < 25; ++j) d2r[j] = s2[le * 25 + j];

        // ---- c-split compute: sub0 c=t, sub1 c=4+t (t=3 masked for sub1) ----
        #pragma unroll
        for (int t = 0; t < 4; ++t) {
            const int c = sub * 4 + t;
            if (c < 7) {
                // U coefficients for this c: 2 distinct addrs/wave -> broadcast
                float cgv[15];
                #pragma unroll
                for (int i = 0; i < 3; ++i)
                    #pragma unroll
                    for (int j = 0; j < 5; ++j)
                        cgv[i * 5 + j] = scg[i * 35 + j * 7 + c];
                // D3 column c: stride 49 (coprime 32), halves offset +4 -> 2-way = free
                float d3c[7];
                #pragma unroll
                for (int i = 0; i < 7; ++i) d3c[i] = s3[le * 49 + i * 7 + c];

                #pragma unroll
                for (int a = 0; a < 3; ++a) {
                    float U[5];
                    #pragma unroll
                    for (int j = 0; j < 5; ++j)
                        U[j] = fmaf(d1[a * 3 + 2], cgv[10 + j],
                               fmaf(d1[a * 3 + 1], cgv[5 + j],
                                    d1[a * 3 + 0] * cgv[j]));
                    #pragma unroll
                    for (int b = 0; b < 5; ++b) {
                        float L = d2r[b * 5] * U[0];
                        #pragma unroll
                        for (int j = 1; j < 5; ++j) L = fmaf(d2r[b * 5 + j], U[j], L);
                        // R-part cg: compile-time index, wave-uniform -> s_load/SGPR
                        float R = cg[(a * 5 + b) * 7] * d3c[0];
                        #pragma unroll
                        for (int i = 1; i < 7; ++i) R = fmaf(cg[(a * 5 + b) * 7 + i], d3c[i], R);
                        const float r = L - R;
                        acc = fmaf(r, r, acc);
                    }
                }
            }
        }
    }

    // wave butterfly (sums both subs of each element pair) -> one partial/wave
    #pragma unroll
    for (int off = 32; off > 0; off >>= 1)
        acc += __shfl_down(acc, off, 64);
    if (l == 0) partials[gw] = acc;
}

__global__ __launch_bounds__(256) void cg_reduce_kernel(
    const float* __restrict__ partials, float* __restrict__ out,
    int n, float inv)
{
    const int tid = threadIdx.x;
    float s = 0.0f;
    for (int i = tid; i < n; i += 256) s += partials[i];   // deterministic order
    #pragma unroll
    for (int off = 32; off > 0; off >>= 1)
        s += __shfl_down(s, off, 64);
    __shared__ float wsum[4];
    if ((tid & 63) == 0) wsum[tid >> 6] = s;
    __syncthreads();
    if (tid == 0) {
        float t = 0.0f;
        #pragma unroll
        for (int w = 0; w < 4; ++w) t += wsum[w];
        out[0] = t * inv;
    }
}

extern "C" void kernel_launch(void* const* d_in, const int* in_sizes, int n_in,
                              void* d_out, int out_size, void* d_ws, size_t ws_size,
                              hipStream_t stream)
{
    const float* D1 = (const float*)d_in[0];
    const float* D2 = (const float*)d_in[1];
    const float* D3 = (const float*)d_in[2];
    const float* cg = (const float*)d_in[3];
    float* out      = (float*)d_out;
    float* partials = (float*)d_ws;          // 4096 floats = 16 KB scratch

    const int batch = in_sizes[0] / 9;       // 262144
    const float inv = 1.0f / ((float)batch * 105.0f);

    cg_main_kernel<<<NBLOCKS, 256, 0, stream>>>(D1, D2, D3, cg, partials);
    cg_reduce_kernel<<<1, 256, 0, stream>>>(partials, out, NWAVES, inv);
}